// Round 1
// baseline (64.834 us; speedup 1.0000x reference)
//
#include <hip/hip_runtime.h>
#include <math.h>

#define BATCH 2048
#define FEAT 128
#define RULES 512
#define RES 5

__device__ __forceinline__ float fast_rcp(float v) { return __builtin_amdgcn_rcpf(v); }

// One block (256 threads = 4 waves) per batch row; 2 rules per thread.
// 2048 blocks -> 8192 waves -> 8 waves/SIMD (was 2): the shuffle/exp latency
// chains that dominate this tiny kernel now overlap across 4x more waves.
// Each thread only needs softmax(b) for its OWN two rules -> beliefs stay in
// registers; the 10KB LDS belief table, its block-wide softmax phase, and the
// 40 LDS reads/lane of the old structure are gone. a/r/b loads are fully
// coalesced float2s (b was a stride-20B scalar pattern before).
__global__ __launch_bounds__(256, 8) void fuzzy_er_kernel(
    const float* __restrict__ x, const float* __restrict__ a,
    const float* __restrict__ b, const float* __restrict__ r,
    const float* __restrict__ d, float* __restrict__ out)
{
    __shared__ float s_part[4];
    __shared__ float p_part[4][RES];

    const int tid  = threadIdx.x;
    const int wave = tid >> 6;
    const int lane = tid & 63;
    const int row  = blockIdx.x;

    // ---- issue all global loads up front (x is the per-row cold load) ----
    const float2 xv = *(const float2*)(x + row * FEAT + lane * 2);
    const float2 av = *(const float2*)(a + tid * 2);
    const float2 rv = *(const float2*)(r + tid * 2);
    const float2* bp = (const float2*)(b + tid * 2 * RES);  // 10 floats, 8B-aligned
    const float2 b0 = bp[0], b1 = bp[1], b2 = bp[2], b3 = bp[3], b4 = bp[4];
    const float ed = __expf(d[0]);

    // ---- per-thread softmax of b for rules (2*tid, 2*tid+1), in registers ----
    // rule 2*tid   : b0.x b0.y b1.x b1.y b2.x
    float e0 = __expf(b0.x), e1 = __expf(b0.y), e2 = __expf(b1.x),
          e3 = __expf(b1.y), e4 = __expf(b2.x);
    float inv0 = fast_rcp(e0 + e1 + e2 + e3 + e4);
    float bel0[RES] = {e0 * inv0, e1 * inv0, e2 * inv0, e3 * inv0, e4 * inv0};
    // rule 2*tid+1 : b2.y b3.x b3.y b4.x b4.y
    float f0 = __expf(b2.y), f1 = __expf(b3.x), f2 = __expf(b3.y),
          f3 = __expf(b4.x), f4 = __expf(b4.y);
    float inv1 = fast_rcp(f0 + f1 + f2 + f3 + f4);
    float bel1[RES] = {f0 * inv1, f1 * inv1, f2 * inv1, f3 * inv1, f4 * inv1};

    // ---- row feature sums (each wave computes them redundantly; no barrier) ----
    float x1 = xv.x * 0.2f, x2 = xv.y * 0.2f;
    float sx  = x1 + x2;
    float sxx = x1 * x1 + x2 * x2;
    #pragma unroll
    for (int off = 32; off > 0; off >>= 1) {
        sx  += __shfl_xor(sx,  off, 64);
        sxx += __shfl_xor(sxx, off, 64);
    }

    // ---- rule activations: aw = exp(r - ed*(128 a^2 - 2 a Sx + Sxx)) ----
    float t0 = (fmaf(128.0f * av.x, av.x, sxx) - 2.0f * av.x * sx) * ed;
    float t1 = (fmaf(128.0f * av.y, av.y, sxx) - 2.0f * av.y * sx) * ed;
    float aw0 = __expf(rv.x - t0);
    float aw1 = __expf(rv.y - t1);

    // ---- block-level s = sum(aw) ----
    float ws = aw0 + aw1;
    #pragma unroll
    for (int off = 32; off > 0; off >>= 1) ws += __shfl_xor(ws, off, 64);
    if (lane == 0) s_part[wave] = ws;
    __syncthreads();
    const float s = (s_part[0] + s_part[1]) + (s_part[2] + s_part[3]);

    // ---- evidential-reasoning combine over this thread's 2 rules ----
    float ratio0 = aw0 * fast_rcp(s - aw0);
    float ratio1 = aw1 * fast_rcp(s - aw1);
    float prod[RES];
    #pragma unroll
    for (int q = 0; q < RES; ++q)
        prod[q] = fmaf(ratio0, bel0[q], 1.0f) * fmaf(ratio1, bel1[q], 1.0f);

    // ---- block-level product over all 512 rules ----
    #pragma unroll
    for (int off = 32; off > 0; off >>= 1) {
        #pragma unroll
        for (int q = 0; q < RES; ++q)
            prod[q] *= __shfl_xor(prod[q], off, 64);
    }
    if (lane == 0) {
        #pragma unroll
        for (int q = 0; q < RES; ++q) p_part[wave][q] = prod[q];
    }
    __syncthreads();

    if (tid == 0) {
        float bc[RES], sbc = 0.0f;
        #pragma unroll
        for (int q = 0; q < RES; ++q) {
            bc[q] = (p_part[0][q] * p_part[1][q]) * (p_part[2][q] * p_part[3][q]) - 1.0f;
            sbc += bc[q];
        }
        // u = [-0.5, 0, 0.5, 1.0, 1.5]
        float num = fmaf(1.5f, bc[4], fmaf(0.5f, bc[2], bc[3])) - 0.5f * bc[0];
        out[row] = num * fast_rcp(sbc);
    }
}

extern "C" void kernel_launch(void* const* d_in, const int* in_sizes, int n_in,
                              void* d_out, int out_size, void* d_ws, size_t ws_size,
                              hipStream_t stream) {
    const float* x = (const float*)d_in[0];
    const float* a = (const float*)d_in[1];
    const float* b = (const float*)d_in[2];
    const float* r = (const float*)d_in[3];
    const float* d = (const float*)d_in[4];
    float* out = (float*)d_out;

    fuzzy_er_kernel<<<BATCH, 256, 0, stream>>>(x, a, b, r, d, out);
}